// Round 6
// baseline (247.930 us; speedup 1.0000x reference)
//
#include <hip/hip_runtime.h>

// PillarMaxPooling R18: write-combined counting sort + LDS pool.
// Invariant from R12-R17: scatter cost ∝ random point-line TOUCHES (~800k);
// insensitive to op count (R13), latency (R15), packing (R16), XCD placement
// (R17: null -> device atomics execute at shared fabric regardless). Only
// remaining lever: reduce touches by pre-combining. R14's sort failed because
// its pass-2 wrote per-point records at globally interleaved cursor slots
// (same 800k touches). Fix: TILE-LOCAL counting sort -- each block sorts a
// 2048-pt tile in LDS, allocates ONE contiguous global segment per
// (tile,bucket) (240k allocs), copies records in sorted order => consecutive
// threads write adjacent slots => coalesced (~70 rec/segment). Pass-3 = R14's
// pool (proven, never the bottleneck): 256 pillars/block, 32KB LDS max, LDS
// atomicMax, stats folded, single coalesced output write, no out memset.
// Fallback to proven R12 path if nbkt>512 or ws too small (R14: ws>=29MB ok).
// Ledger: R12 85.8us/172 best; R13 no-filter 94; R14 global-cursor sort 286;
// R15 pipeline 92; R16 f16 108; R17 partition 90-97. Harness ~85us.

#define CMLP 32
#define BN_EPS 1e-3f
#define PSIZE 0.075f
#define XMIN -54.0f
#define YMIN -54.0f
#define CZ   -1.0f   // 0.5*(Z_MIN+Z_MAX)
#define NREP 64      // stats replicas (64 lines apart)
#define SCATB 4096   // fallback scatter blocks
#define BSH 8        // pillars-per-bucket shift (256 pillars/bucket)
#define PPB3 256     // pillars per pool block
#define MAXBKT 512   // LDS array bound; fallback if nbkt > this
#define TPTS 2048    // sort tile size (points)
#define NBLK2 256    // sort blocks
#define HISTB 1024

// monotone float<->uint order map; u==0 unreachable from real data -> sentinel
__device__ __forceinline__ unsigned enc_f(float x) {
  unsigned b = __float_as_uint(x);
  return (b & 0x80000000u) ? ~b : (b | 0x80000000u);
}
__device__ __forceinline__ float dec_f(unsigned u) {
  unsigned b = (u & 0x80000000u) ? (u & 0x7fffffffu) : ~u;
  return __uint_as_float(b);
}

// ---------------- pass 1: bucket histogram (LDS pre-reduced) ----------------
__global__ void __launch_bounds__(256) hist_kernel(
    const int* __restrict__ sidx, int* __restrict__ hist, int N, int nbkt) {
  __shared__ int h[MAXBKT];
  for (int b = threadIdx.x; b < MAXBKT; b += 256) h[b] = 0;
  __syncthreads();
  const int stride = gridDim.x * 256;
  for (int p = blockIdx.x * 256 + threadIdx.x; p < N; p += stride)
    atomicAdd(&h[__builtin_nontemporal_load(&sidx[p]) >> BSH], 1);
  __syncthreads();
  for (int b = threadIdx.x; b < nbkt; b += 256)
    if (h[b]) atomicAdd(&hist[b], h[b]);
}

// ---------------- pass 1b: exclusive prefix + cursor init ----------------
__global__ void __launch_bounds__(512) prefix_kernel(
    const int* __restrict__ hist, int* __restrict__ offs,
    int* __restrict__ cur, int nbkt) {
  __shared__ int sh[MAXBKT + 1];
  const int t = threadIdx.x;
  if (t < MAXBKT) sh[t] = (t < nbkt) ? hist[t] : 0;
  __syncthreads();
  if (t == 0) {
    int acc = 0;
    for (int i = 0; i < nbkt; i++) { int v = sh[i]; sh[i] = acc; acc += v; }
    sh[nbkt] = acc;
  }
  __syncthreads();
  if (t <= nbkt) {
    offs[t] = sh[t];
    if (t < nbkt) cur[t] = sh[t];
  }
}

// ---------------- pass 2: tile-local sort, coalesced record writes ----------
__global__ void __launch_bounds__(256) sort_kernel(
    const float* __restrict__ xyz, const float* __restrict__ ptf,
    const int* __restrict__ sidx, int* __restrict__ cur,
    float4* __restrict__ recA, float4* __restrict__ recB,
    float* __restrict__ recC, int N) {
  __shared__ int lds_m[TPTS];                // 8KB: pillar idx per tile point
  __shared__ unsigned short srt[TPTS];       // 4KB: tile-sorted point order
  __shared__ int cnt[MAXBKT], base[MAXBKT], off[MAXBKT], fill[MAXBKT];  // 8KB
  const int tid = threadIdx.x;
  const int chunk = (N + NBLK2 - 1) / NBLK2;
  const int lo = blockIdx.x * chunk;
  const int hi = (lo + chunk < N) ? lo + chunk : N;
  for (int t0 = lo; t0 < hi; t0 += TPTS) {
    const int tn = (TPTS < hi - t0) ? TPTS : hi - t0;
    // phase A: load m, LDS count
    for (int b = tid; b < MAXBKT; b += 256) cnt[b] = 0;
    __syncthreads();
    for (int i = tid; i < tn; i += 256) {
      int m = __builtin_nontemporal_load(&sidx[t0 + i]);
      lds_m[i] = m;
      atomicAdd(&cnt[m >> BSH], 1);
    }
    __syncthreads();
    // tile-local exclusive prefix (thread 0 over LDS: fast)
    if (tid == 0) {
      int acc = 0;
      for (int b = 0; b < MAXBKT; b++) { int v = cnt[b]; off[b] = acc; acc += v; }
    }
    __syncthreads();
    // one global segment per (tile,bucket)
    for (int b = tid; b < MAXBKT; b += 256) {
      base[b] = cnt[b] ? atomicAdd(&cur[b], cnt[b]) : 0;
      fill[b] = 0;
    }
    __syncthreads();
    // phase B: scatter indices into tile-sorted LDS order
    for (int i = tid; i < tn; i += 256) {
      int b = lds_m[i] >> BSH;
      int r = atomicAdd(&fill[b], 1);
      srt[off[b] + r] = (unsigned short)i;
    }
    __syncthreads();
    // phase C: copy records in sorted order -> adjacent threads hit adjacent
    // global slots of the same bucket segment => coalesced line writes
    for (int j = tid; j < tn; j += 256) {
      int i = srt[j];
      int p = t0 + i;
      int m = lds_m[i];
      int b = m >> BSH;
      int idx = base[b] + (j - off[b]);
      recA[idx] = make_float4(xyz[3 * p], xyz[3 * p + 1], xyz[3 * p + 2],
                              __int_as_float(m));
      recB[idx] = make_float4(ptf[5 * p], ptf[5 * p + 1], ptf[5 * p + 2],
                              ptf[5 * p + 3]);
      recC[idx] = ptf[5 * p + 4];
    }
    __syncthreads();  // LDS reused next tile
  }
}

// ---------------- pass 3: per-bucket LDS max-pool + BN stats ----------------
__global__ void __launch_bounds__(512) pool_kernel(
    const float4* __restrict__ recA, const float4* __restrict__ recB,
    const float* __restrict__ recC, const int* __restrict__ offs,
    const float* __restrict__ W1, const float* __restrict__ gamma,
    const int* __restrict__ pil, float* __restrict__ stats_rep,
    unsigned* __restrict__ outenc, int M) {
  __shared__ unsigned lmax[PPB3 * CMLP];  // 32KB
  const int tid = threadIdx.x;
  const int c = tid & 31;
  for (int k = tid; k < PPB3 * CMLP; k += 512) lmax[k] = 0u;
  // folded weights: h = x*wx + y*wy + z*wz - cx*w0 - cy*w1 - CZ*w2 + ptf.w
  const float w0 = W1[0 * CMLP + c], w1 = W1[1 * CMLP + c];
  const float w2 = W1[2 * CMLP + c];
  const float wx = w0 + W1[3 * CMLP + c];
  const float wy = w1 + W1[4 * CMLP + c];
  const float wz = w2 + W1[5 * CMLP + c];
  const float nw0 = -w0, nw1 = -w1;
  const float cc0 = -CZ * w2;
  const float w6 = W1[6 * CMLP + c], w7 = W1[7 * CMLP + c];
  const float w8 = W1[8 * CMLP + c], w9 = W1[9 * CMLP + c];
  const float w10 = W1[10 * CMLP + c];
  const float sgn = (gamma[c] < 0.f) ? -1.f : 1.f;
  const int b = blockIdx.x;
  const int base = offs[b], end = offs[b + 1];
  const int p0 = b << BSH;
  float s = 0.f, ss = 0.f;
  __syncthreads();
  // 16 half-waves; 32 lanes of a half-wave read the SAME record -> broadcast
  for (int i = base + (tid >> 5); i < end; i += 16) {
    float4 a = recA[i];
    float4 f = recB[i];
    float f4 = recC[i];
    int m = __float_as_int(a.w);
    // pil window for this bucket = 256 rows * 12B = 3KB -> L2-resident
    float cx = fmaf((float)pil[3 * m + 2] + 0.5f, PSIZE, XMIN);
    float cy = fmaf((float)pil[3 * m + 1] + 0.5f, PSIZE, YMIN);
    float h = cc0;
    h = fmaf(a.x, wx, h);
    h = fmaf(a.y, wy, h);
    h = fmaf(a.z, wz, h);
    h = fmaf(cx, nw0, h);
    h = fmaf(cy, nw1, h);
    h = fmaf(f.x, w6, h);
    h = fmaf(f.y, w7, h);
    h = fmaf(f.z, w8, h);
    h = fmaf(f.w, w9, h);
    h = fmaf(f4, w10, h);
    s += h;
    ss = fmaf(h, h, ss);
    atomicMax(&lmax[((m - p0) << 5) | c], enc_f(sgn * h));  // LDS: cheap
  }
  __syncthreads();
  // coalesced one-shot output write (covers all elements -> no memset)
  const int gbase = b * (PPB3 * CMLP);
  const int glim = M * CMLP;
  for (int k = tid; k < PPB3 * CMLP; k += 512) {
    int g = gbase + k;
    if (g < glim) outenc[g] = lmax[k];
  }
  // BN stats reduce (8 waves)
  s += __shfl_xor(s, 32);
  ss += __shfl_xor(ss, 32);
  __shared__ float red[8][64];
  const int wave = tid >> 6, lane = tid & 63;
  if (lane < 32) {
    red[wave][lane] = s;
    red[wave][32 + lane] = ss;
  }
  __syncthreads();
  if (tid < 64) {
    float v = 0.f;
#pragma unroll
    for (int w = 0; w < 8; w++) v += red[w][tid];
    atomicAdd(&stats_rep[(blockIdx.x & (NREP - 1)) * 64 + tid], v);
  }
}

// ---------------- fallback: proven R12 filtered scatter ----------------
__global__ void __launch_bounds__(256) scatter_stats_kernel(
    const float* __restrict__ xyz, const float* __restrict__ ptf,
    const float* __restrict__ W1, const float* __restrict__ gamma,
    const int* __restrict__ pil, const int* __restrict__ sidx,
    float* __restrict__ stats_rep, unsigned* __restrict__ outenc, int N) {
  const int tid = threadIdx.x;
  const int c = tid & 31;
  const float w0 = W1[0 * CMLP + c], w1 = W1[1 * CMLP + c];
  const float w2 = W1[2 * CMLP + c];
  const float wx = w0 + W1[3 * CMLP + c];
  const float wy = w1 + W1[4 * CMLP + c];
  const float wz = w2 + W1[5 * CMLP + c];
  const float nw0 = -w0, nw1 = -w1;
  const float cc0 = -CZ * w2;
  const float w6 = W1[6 * CMLP + c], w7 = W1[7 * CMLP + c];
  const float w8 = W1[8 * CMLP + c], w9 = W1[9 * CMLP + c];
  const float w10 = W1[10 * CMLP + c];
  const float sgn = (gamma[c] < 0.f) ? -1.f : 1.f;
  float s = 0.f, ss = 0.f;
  const int hw0 = (blockIdx.x * 256 + tid) >> 5;
  const int nhw = (SCATB * 256) >> 5;
  int p = hw0;
  int m = (p < N) ? sidx[p] : 0;
  while (p < N) {
    const int pn = p + nhw;
    const int mn = (pn < N) ? sidx[pn] : 0;
    float cx = fmaf((float)pil[3 * m + 2] + 0.5f, PSIZE, XMIN);
    float cy = fmaf((float)pil[3 * m + 1] + 0.5f, PSIZE, YMIN);
    float x = xyz[3 * p], y = xyz[3 * p + 1], z = xyz[3 * p + 2];
    float h = cc0;
    h = fmaf(x, wx, h);
    h = fmaf(y, wy, h);
    h = fmaf(z, wz, h);
    h = fmaf(cx, nw0, h);
    h = fmaf(cy, nw1, h);
    h = fmaf(ptf[5 * p + 0], w6, h);
    h = fmaf(ptf[5 * p + 1], w7, h);
    h = fmaf(ptf[5 * p + 2], w8, h);
    h = fmaf(ptf[5 * p + 3], w9, h);
    h = fmaf(ptf[5 * p + 4], w10, h);
    s += h;
    ss = fmaf(h, h, ss);
    unsigned u = enc_f(sgn * h);
    unsigned* addr = &outenc[m * CMLP + c];
    if (u > *addr) atomicMax(addr, u);
    p = pn;
    m = mn;
  }
  s += __shfl_xor(s, 32);
  ss += __shfl_xor(ss, 32);
  __shared__ float red[4][64];
  const int wave = tid >> 6, lane = tid & 63;
  if (lane < 32) {
    red[wave][lane] = s;
    red[wave][32 + lane] = ss;
  }
  __syncthreads();
  if (tid < 64) {
    float v = red[0][tid] + red[1][tid] + red[2][tid] + red[3][tid];
    atomicAdd(&stats_rep[(blockIdx.x & (NREP - 1)) * 64 + tid], v);
  }
}

__global__ void finalize_kernel(const float* __restrict__ gamma,
                                const float* __restrict__ beta,
                                const float* __restrict__ stats_rep,
                                float* __restrict__ affine, float invN) {
  int c = threadIdx.x;
  if (c < CMLP) {
    float s = 0.f, ss = 0.f;
    for (int r = 0; r < NREP; r++) {
      s += stats_rep[r * 64 + c];
      ss += stats_rep[r * 64 + 32 + c];
    }
    float mean = s * invN;
    float var = ss * invN - mean * mean;          // biased, like jnp.var
    float sc = gamma[c] * rsqrtf(var + BN_EPS);
    affine[c] = sc;                               // scale
    affine[CMLP + c] = beta[c] - mean * sc;       // bias
  }
}

__global__ void __launch_bounds__(256) transform_kernel(
    unsigned* __restrict__ io, const float* __restrict__ affine, int total) {
  int i = blockIdx.x * 256 + threadIdx.x;
  if (i < total) {
    unsigned u = io[i];
    int c = i & 31;
    float v = 0.f;  // u==0 <=> empty pillar -> 0 (max-then-relu floor)
    if (u) v = fmaxf(fmaf(fabsf(affine[c]), dec_f(u), affine[CMLP + c]), 0.f);
    io[i] = __float_as_uint(v);
  }
}

extern "C" void kernel_launch(void* const* d_in, const int* in_sizes, int n_in,
                              void* d_out, int out_size, void* d_ws, size_t ws_size,
                              hipStream_t stream) {
  const float* xyz = (const float*)d_in[0];
  const float* ptf = (const float*)d_in[1];
  const float* W1 = (const float*)d_in[2];
  const float* gamma = (const float*)d_in[3];
  const float* beta = (const float*)d_in[4];
  const int* pil = (const int*)d_in[5];
  const int* sidx = (const int*)d_in[6];
  unsigned* out = (unsigned*)d_out;

  int N = in_sizes[0] / 3;
  int M = out_size / CMLP;
  int nbkt = (M + PPB3 - 1) / PPB3;

  // workspace layout
  char* w = (char*)d_ws;
  float* stats_rep = (float*)w;              size_t off = NREP * 64 * sizeof(float);
  float* affine = (float*)(w + off);         off += 64 * sizeof(float);
  int* hist = (int*)(w + off);               off += MAXBKT * sizeof(int);
  int* offs = (int*)(w + off);               off += (MAXBKT + 1) * sizeof(int);
  int* cur = (int*)(w + off);                off += MAXBKT * sizeof(int);
  off = (off + 15) & ~(size_t)15;
  float4* recA = (float4*)(w + off);         off += (size_t)N * sizeof(float4);
  float4* recB = (float4*)(w + off);         off += (size_t)N * sizeof(float4);
  float* recC = (float*)(w + off);           off += (size_t)N * sizeof(float);

  hipMemsetAsync(stats_rep, 0, NREP * 64 * sizeof(float), stream);

  if (nbkt <= MAXBKT && ws_size >= off) {
    // ---- write-combined sort pipeline ----
    hipMemsetAsync(hist, 0, MAXBKT * sizeof(int), stream);
    hist_kernel<<<HISTB, 256, 0, stream>>>(sidx, hist, N, nbkt);
    prefix_kernel<<<1, 512, 0, stream>>>(hist, offs, cur, nbkt);
    sort_kernel<<<NBLK2, 256, 0, stream>>>(xyz, ptf, sidx, cur,
                                           recA, recB, recC, N);
    pool_kernel<<<nbkt, 512, 0, stream>>>(recA, recB, recC, offs, W1, gamma,
                                          pil, stats_rep, out, M);
  } else {
    // ---- fallback: proven R12 path ----
    hipMemsetAsync(out, 0, (size_t)out_size * sizeof(unsigned), stream);
    scatter_stats_kernel<<<SCATB, 256, 0, stream>>>(xyz, ptf, W1, gamma, pil,
                                                    sidx, stats_rep, out, N);
  }
  finalize_kernel<<<1, 64, 0, stream>>>(gamma, beta, stats_rep, affine,
                                        1.0f / (float)N);
  transform_kernel<<<(out_size + 255) / 256, 256, 0, stream>>>(out, affine,
                                                               out_size);
}

// Round 7
// 243.678 us; speedup vs baseline: 1.0174x; 1.0174x over previous
//
#include <hip/hip_runtime.h>

// PillarMaxPooling R19: de-serialized sort + pool pipeline.
// R18 post-mortem: concept not refuted -- both passes latency/serialization
// bound, nothing saturated. pool 76.7us: dependent pil gather per record +
// grid 469 blk -> 35% occ. sort ~74us (by subtraction): 4 waves/CU, serial
// thread-0 prefix per tile, useless srt permutation phase.
// Fixes: sort = 196 blk x 1024 thr, TPTS 4096, direct segment write (no
// prefix/srt), pack (px,py,m&127) into recA.w so pool never touches pil.
// pool = BSH 7 (128 pillars, 16KB lmax) -> 938 blk x 512 thr = ~30 waves/CU,
// depth-1 prefetch, critical path = FMA chain + LDS atomic only.
// Invariant (R12-R17): random-line-touch fabric traffic is the enemy; sort
// segments (avg 4.4 rec) cut record-write touches ~4x vs per-point scatter.
// Fallback = proven R12 scatter (85.8us) if ws/nbkt don't fit.
// Ledger: R12 172 total best; R13 94; R14 286; R15 92; R16 108; R17 90-97;
// R18 248 (pool 77, sort ~74). Harness ~85us constant.

#define CMLP 32
#define BN_EPS 1e-3f
#define PSIZE 0.075f
#define XMIN -54.0f
#define YMIN -54.0f
#define CZ   -1.0f   // 0.5*(Z_MIN+Z_MAX)
#define NREP 64      // stats replicas (64 lines apart)
#define SCATB 4096   // fallback scatter blocks
#define BSH 7        // pillars-per-bucket shift (128 pillars/bucket)
#define PPB3 128     // pillars per pool block
#define MAXBKT 1024  // array bound; fallback if nbkt > this
#define TPTS 4096    // sort tile size (points)
#define STHREADS 1024
#define HISTB 1024
#define CURSTR 32    // cur stride in ints (128B apart -> no hot-line alloc)

// monotone float<->uint order map; u==0 unreachable from real data -> sentinel
__device__ __forceinline__ unsigned enc_f(float x) {
  unsigned b = __float_as_uint(x);
  return (b & 0x80000000u) ? ~b : (b | 0x80000000u);
}
__device__ __forceinline__ float dec_f(unsigned u) {
  unsigned b = (u & 0x80000000u) ? (u & 0x7fffffffu) : ~u;
  return __uint_as_float(b);
}

// ---------------- pass 1: bucket histogram (LDS pre-reduced) ----------------
__global__ void __launch_bounds__(256) hist_kernel(
    const int* __restrict__ sidx, int* __restrict__ hist, int N, int nbkt) {
  __shared__ int h[MAXBKT];
  for (int b = threadIdx.x; b < MAXBKT; b += 256) h[b] = 0;
  __syncthreads();
  const int stride = gridDim.x * 256;
  for (int p = blockIdx.x * 256 + threadIdx.x; p < N; p += stride)
    atomicAdd(&h[__builtin_nontemporal_load(&sidx[p]) >> BSH], 1);
  __syncthreads();
  for (int b = threadIdx.x; b < nbkt; b += 256)
    if (h[b]) atomicAdd(&hist[b], h[b]);
}

// ---------------- pass 1b: global exclusive prefix + cursor init -----------
__global__ void __launch_bounds__(1024) prefix_kernel(
    const int* __restrict__ hist, int* __restrict__ offs,
    int* __restrict__ cur, int nbkt) {
  __shared__ int sh[MAXBKT + 1];
  const int t = threadIdx.x;
  if (t < MAXBKT) sh[t] = (t < nbkt) ? hist[t] : 0;
  __syncthreads();
  if (t == 0) {  // serial over LDS (~1k entries): fast enough once-per-launch
    int acc = 0;
    for (int i = 0; i < nbkt; i++) { int v = sh[i]; sh[i] = acc; acc += v; }
    sh[nbkt] = acc;
  }
  __syncthreads();
  if (t < nbkt) {
    offs[t] = sh[t];
    cur[t * CURSTR] = sh[t];
  }
  if (t == 0) offs[nbkt] = sh[nbkt];
}

// ---------------- pass 2: tile-local count + direct segment write ----------
// record: recA=(x,y,z,pack) recB=(f0..f3) recC=f4; pack=px|py<<11|(m&127)<<22
__global__ void __launch_bounds__(STHREADS) sort_kernel(
    const float* __restrict__ xyz, const float* __restrict__ ptf,
    const int* __restrict__ pil, const int* __restrict__ sidx,
    int* __restrict__ cur, float4* __restrict__ recA,
    float4* __restrict__ recB, float* __restrict__ recC, int N) {
  __shared__ int lds_m[TPTS];   // 16KB
  __shared__ int cnt[MAXBKT];   // 4KB
  __shared__ int base[MAXBKT];  // 4KB
  __shared__ int fill[MAXBKT];  // 4KB
  const int tid = threadIdx.x;
  const int t0 = blockIdx.x * TPTS;
  const int tn = (TPTS < N - t0) ? TPTS : N - t0;
  for (int b = tid; b < MAXBKT; b += STHREADS) cnt[b] = 0;
  __syncthreads();
  // count (4 iters, coalesced NT stream)
  for (int i = tid; i < tn; i += STHREADS) {
    int m = __builtin_nontemporal_load(&sidx[t0 + i]);
    lds_m[i] = m;
    atomicAdd(&cnt[m >> BSH], 1);
  }
  __syncthreads();
  // one contiguous global segment per (tile,bucket); cur strided 128B
  for (int b = tid; b < MAXBKT; b += STHREADS) {
    base[b] = cnt[b] ? atomicAdd(&cur[b * CURSTR], cnt[b]) : 0;
    fill[b] = 0;
  }
  __syncthreads();
  // direct write: order within a segment irrelevant (same lines either way)
  for (int i = tid; i < tn; i += STHREADS) {
    const int m = lds_m[i];
    const int b = m >> BSH;
    const int p = t0 + i;
    const int px = pil[3 * m + 2];            // random, L2-resident table
    const int py = pil[3 * m + 1];
    const unsigned pack = (unsigned)px | ((unsigned)py << 11) |
                          ((unsigned)(m & (PPB3 - 1)) << 22);
    const int idx = base[b] + atomicAdd(&fill[b], 1);
    recA[idx] = make_float4(__builtin_nontemporal_load(&xyz[3 * p]),
                            __builtin_nontemporal_load(&xyz[3 * p + 1]),
                            __builtin_nontemporal_load(&xyz[3 * p + 2]),
                            __uint_as_float(pack));
    recB[idx] = make_float4(__builtin_nontemporal_load(&ptf[5 * p]),
                            __builtin_nontemporal_load(&ptf[5 * p + 1]),
                            __builtin_nontemporal_load(&ptf[5 * p + 2]),
                            __builtin_nontemporal_load(&ptf[5 * p + 3]));
    recC[idx] = __builtin_nontemporal_load(&ptf[5 * p + 4]);
  }
}

// ---------------- pass 3: per-bucket LDS max-pool + BN stats ----------------
__global__ void __launch_bounds__(512) pool_kernel(
    const float4* __restrict__ recA, const float4* __restrict__ recB,
    const float* __restrict__ recC, const int* __restrict__ offs,
    const float* __restrict__ W1, const float* __restrict__ gamma,
    float* __restrict__ stats_rep, unsigned* __restrict__ outenc, int M) {
  __shared__ unsigned lmax[PPB3 * CMLP];  // 16KB
  const int tid = threadIdx.x;
  const int c = tid & 31;
  for (int k = tid; k < PPB3 * CMLP; k += 512) lmax[k] = 0u;
  // folded weights: h = x*wx + y*wy + z*wz - cx*w0 - cy*w1 - CZ*w2 + ptf.w
  const float w0 = W1[0 * CMLP + c], w1 = W1[1 * CMLP + c];
  const float w2 = W1[2 * CMLP + c];
  const float wx = w0 + W1[3 * CMLP + c];
  const float wy = w1 + W1[4 * CMLP + c];
  const float wz = w2 + W1[5 * CMLP + c];
  const float nw0 = -w0, nw1 = -w1;
  const float cc0 = -CZ * w2;
  const float w6 = W1[6 * CMLP + c], w7 = W1[7 * CMLP + c];
  const float w8 = W1[8 * CMLP + c], w9 = W1[9 * CMLP + c];
  const float w10 = W1[10 * CMLP + c];
  const float sgn = (gamma[c] < 0.f) ? -1.f : 1.f;
  const int b = blockIdx.x;
  const int rbase = offs[b], rend = offs[b + 1];
  float s = 0.f, ss = 0.f;
  __syncthreads();
  // 16 half-waves; 32 lanes read the SAME record -> HW broadcast.
  // depth-1 prefetch: all loads for iter i+1 issued before consuming iter i.
  int i = rbase + (tid >> 5);
  float4 a = make_float4(0.f, 0.f, 0.f, 0.f);
  float4 f = make_float4(0.f, 0.f, 0.f, 0.f);
  float f4c = 0.f;
  if (i < rend) { a = recA[i]; f = recB[i]; f4c = recC[i]; }
  while (i < rend) {
    const int inext = i + 16;
    float4 an = make_float4(0.f, 0.f, 0.f, 0.f);
    float4 fn = make_float4(0.f, 0.f, 0.f, 0.f);
    float f4n = 0.f;
    if (inext < rend) { an = recA[inext]; fn = recB[inext]; f4n = recC[inext]; }
    const unsigned pack = __float_as_uint(a.w);
    const int px = pack & 0x7FF;
    const int py = (pack >> 11) & 0x7FF;
    const int ml = pack >> 22;  // m & 127 (no higher bits set)
    float cx = fmaf((float)px + 0.5f, PSIZE, XMIN);
    float cy = fmaf((float)py + 0.5f, PSIZE, YMIN);
    float h = cc0;
    h = fmaf(a.x, wx, h);
    h = fmaf(a.y, wy, h);
    h = fmaf(a.z, wz, h);
    h = fmaf(cx, nw0, h);
    h = fmaf(cy, nw1, h);
    h = fmaf(f.x, w6, h);
    h = fmaf(f.y, w7, h);
    h = fmaf(f.z, w8, h);
    h = fmaf(f.w, w9, h);
    h = fmaf(f4c, w10, h);
    s += h;
    ss = fmaf(h, h, ss);
    atomicMax(&lmax[(ml << 5) | c], enc_f(sgn * h));  // LDS, 32 banks clean
    i = inext; a = an; f = fn; f4c = f4n;
  }
  __syncthreads();
  // coalesced one-shot output write (covers all elements -> no memset)
  const int gbase = b * (PPB3 * CMLP);
  const int glim = M * CMLP;
  for (int k = tid; k < PPB3 * CMLP; k += 512) {
    const int g = gbase + k;
    if (g < glim) outenc[g] = lmax[k];
  }
  // BN stats reduce (8 waves)
  s += __shfl_xor(s, 32);
  ss += __shfl_xor(ss, 32);
  __shared__ float red[8][64];
  const int wave = tid >> 6, lane = tid & 63;
  if (lane < 32) {
    red[wave][lane] = s;
    red[wave][32 + lane] = ss;
  }
  __syncthreads();
  if (tid < 64) {
    float v = 0.f;
#pragma unroll
    for (int w = 0; w < 8; w++) v += red[w][tid];
    atomicAdd(&stats_rep[(blockIdx.x & (NREP - 1)) * 64 + tid], v);
  }
}

// ---------------- fallback: proven R12 filtered scatter ----------------
__global__ void __launch_bounds__(256) scatter_stats_kernel(
    const float* __restrict__ xyz, const float* __restrict__ ptf,
    const float* __restrict__ W1, const float* __restrict__ gamma,
    const int* __restrict__ pil, const int* __restrict__ sidx,
    float* __restrict__ stats_rep, unsigned* __restrict__ outenc, int N) {
  const int tid = threadIdx.x;
  const int c = tid & 31;
  const float w0 = W1[0 * CMLP + c], w1 = W1[1 * CMLP + c];
  const float w2 = W1[2 * CMLP + c];
  const float wx = w0 + W1[3 * CMLP + c];
  const float wy = w1 + W1[4 * CMLP + c];
  const float wz = w2 + W1[5 * CMLP + c];
  const float nw0 = -w0, nw1 = -w1;
  const float cc0 = -CZ * w2;
  const float w6 = W1[6 * CMLP + c], w7 = W1[7 * CMLP + c];
  const float w8 = W1[8 * CMLP + c], w9 = W1[9 * CMLP + c];
  const float w10 = W1[10 * CMLP + c];
  const float sgn = (gamma[c] < 0.f) ? -1.f : 1.f;
  float s = 0.f, ss = 0.f;
  const int hw0 = (blockIdx.x * 256 + tid) >> 5;
  const int nhw = (SCATB * 256) >> 5;
  int p = hw0;
  int m = (p < N) ? sidx[p] : 0;
  while (p < N) {
    const int pn = p + nhw;
    const int mn = (pn < N) ? sidx[pn] : 0;
    float cx = fmaf((float)pil[3 * m + 2] + 0.5f, PSIZE, XMIN);
    float cy = fmaf((float)pil[3 * m + 1] + 0.5f, PSIZE, YMIN);
    float x = xyz[3 * p], y = xyz[3 * p + 1], z = xyz[3 * p + 2];
    float h = cc0;
    h = fmaf(x, wx, h);
    h = fmaf(y, wy, h);
    h = fmaf(z, wz, h);
    h = fmaf(cx, nw0, h);
    h = fmaf(cy, nw1, h);
    h = fmaf(ptf[5 * p + 0], w6, h);
    h = fmaf(ptf[5 * p + 1], w7, h);
    h = fmaf(ptf[5 * p + 2], w8, h);
    h = fmaf(ptf[5 * p + 3], w9, h);
    h = fmaf(ptf[5 * p + 4], w10, h);
    s += h;
    ss = fmaf(h, h, ss);
    unsigned u = enc_f(sgn * h);
    unsigned* addr = &outenc[m * CMLP + c];
    if (u > *addr) atomicMax(addr, u);
    p = pn;
    m = mn;
  }
  s += __shfl_xor(s, 32);
  ss += __shfl_xor(ss, 32);
  __shared__ float red[4][64];
  const int wave = tid >> 6, lane = tid & 63;
  if (lane < 32) {
    red[wave][lane] = s;
    red[wave][32 + lane] = ss;
  }
  __syncthreads();
  if (tid < 64) {
    float v = red[0][tid] + red[1][tid] + red[2][tid] + red[3][tid];
    atomicAdd(&stats_rep[(blockIdx.x & (NREP - 1)) * 64 + tid], v);
  }
}

__global__ void finalize_kernel(const float* __restrict__ gamma,
                                const float* __restrict__ beta,
                                const float* __restrict__ stats_rep,
                                float* __restrict__ affine, float invN) {
  int c = threadIdx.x;
  if (c < CMLP) {
    float s = 0.f, ss = 0.f;
    for (int r = 0; r < NREP; r++) {
      s += stats_rep[r * 64 + c];
      ss += stats_rep[r * 64 + 32 + c];
    }
    float mean = s * invN;
    float var = ss * invN - mean * mean;          // biased, like jnp.var
    float sc = gamma[c] * rsqrtf(var + BN_EPS);
    affine[c] = sc;                               // scale
    affine[CMLP + c] = beta[c] - mean * sc;       // bias
  }
}

__global__ void __launch_bounds__(256) transform_kernel(
    unsigned* __restrict__ io, const float* __restrict__ affine, int total) {
  int i = blockIdx.x * 256 + threadIdx.x;
  if (i < total) {
    unsigned u = io[i];
    int c = i & 31;
    float v = 0.f;  // u==0 <=> empty pillar -> 0 (max-then-relu floor)
    if (u) v = fmaxf(fmaf(fabsf(affine[c]), dec_f(u), affine[CMLP + c]), 0.f);
    io[i] = __float_as_uint(v);
  }
}

extern "C" void kernel_launch(void* const* d_in, const int* in_sizes, int n_in,
                              void* d_out, int out_size, void* d_ws, size_t ws_size,
                              hipStream_t stream) {
  const float* xyz = (const float*)d_in[0];
  const float* ptf = (const float*)d_in[1];
  const float* W1 = (const float*)d_in[2];
  const float* gamma = (const float*)d_in[3];
  const float* beta = (const float*)d_in[4];
  const int* pil = (const int*)d_in[5];
  const int* sidx = (const int*)d_in[6];
  unsigned* out = (unsigned*)d_out;

  int N = in_sizes[0] / 3;
  int M = out_size / CMLP;
  int nbkt = (M + PPB3 - 1) / PPB3;

  // workspace layout
  char* w = (char*)d_ws;
  float* stats_rep = (float*)w;              size_t off = NREP * 64 * sizeof(float);
  float* affine = (float*)(w + off);         off += 64 * sizeof(float);
  int* hist = (int*)(w + off);               off += MAXBKT * sizeof(int);
  int* offs = (int*)(w + off);               off += (MAXBKT + 1) * sizeof(int);
  off = (off + 127) & ~(size_t)127;
  int* cur = (int*)(w + off);                off += (size_t)MAXBKT * CURSTR * sizeof(int);
  off = (off + 15) & ~(size_t)15;
  float4* recA = (float4*)(w + off);         off += (size_t)N * sizeof(float4);
  float4* recB = (float4*)(w + off);         off += (size_t)N * sizeof(float4);
  float* recC = (float*)(w + off);           off += (size_t)N * sizeof(float);

  hipMemsetAsync(stats_rep, 0, NREP * 64 * sizeof(float), stream);

  if (nbkt <= MAXBKT && ws_size >= off) {
    // ---- write-combined sort pipeline ----
    hipMemsetAsync(hist, 0, MAXBKT * sizeof(int), stream);
    hist_kernel<<<HISTB, 256, 0, stream>>>(sidx, hist, N, nbkt);
    prefix_kernel<<<1, 1024, 0, stream>>>(hist, offs, cur, nbkt);
    int sblk = (N + TPTS - 1) / TPTS;
    sort_kernel<<<sblk, STHREADS, 0, stream>>>(xyz, ptf, pil, sidx, cur,
                                               recA, recB, recC, N);
    pool_kernel<<<nbkt, 512, 0, stream>>>(recA, recB, recC, offs, W1, gamma,
                                          stats_rep, out, M);
  } else {
    // ---- fallback: proven R12 path ----
    hipMemsetAsync(out, 0, (size_t)out_size * sizeof(unsigned), stream);
    scatter_stats_kernel<<<SCATB, 256, 0, stream>>>(xyz, ptf, W1, gamma, pil,
                                                    sidx, stats_rep, out, N);
  }
  finalize_kernel<<<1, 64, 0, stream>>>(gamma, beta, stats_rep, affine,
                                        1.0f / (float)N);
  transform_kernel<<<(out_size + 255) / 256, 256, 0, stream>>>(out, affine,
                                                               out_size);
}